// Round 10
// baseline (361.290 us; speedup 1.0000x reference)
//
#include <hip/hip_runtime.h>
#include <hip/hip_bf16.h>

// GCN: embed -> (conv -> bn -> relu) x2 -> conv(+relu+pool fused) -> linear
// H = 64.
// R9: CSR packed as int2 (src, weight-bits) -> ONE 8B scatter store per edge
//     in fill_csr (R8 counters: two 4B scatters caused 83MB writeback for
//     6.4MB of data). Convs read the packed entry with a single load.

#define GATHER_BATCH 8

// bf16 helpers (bit ops; RTN-even)
__device__ __forceinline__ float bf2f(unsigned short u) {
    unsigned int x = ((unsigned int)u) << 16;
    return __int_as_float((int)x);
}
__device__ __forceinline__ unsigned short f2bf(float f) {
    unsigned int x = (unsigned int)__float_as_int(f);
    x += 0x7fffu + ((x >> 16) & 1u);
    return (unsigned short)(x >> 16);
}

// ---------- tiny precompute: fold one-hot/numeric linears through Wg0 ----------
__global__ void precompute_mats(const float* __restrict__ W1, const float* __restrict__ b1,
                                const float* __restrict__ W2, const float* __restrict__ b2,
                                const float* __restrict__ Wg0,
                                float* __restrict__ M1, float* __restrict__ M2,
                                float* __restrict__ cvec, int T) {
    int tid = threadIdx.x;
    for (int idx = tid; idx < T * 64; idx += blockDim.x) {
        int t = idx >> 6, c = idx & 63;
        float a = 0.f;
        for (int k = 0; k < 64; ++k) a += W1[t * 64 + k] * Wg0[k * 64 + c];
        M1[idx] = a;
    }
    for (int idx = tid; idx < 5 * 64; idx += blockDim.x) {
        int j = idx >> 6, c = idx & 63;
        float a = 0.f;
        for (int k = 0; k < 64; ++k) a += W2[j * 64 + k] * Wg0[(64 + k) * 64 + c];
        M2[idx] = a;
    }
    for (int c = tid; c < 64; c += blockDim.x) {
        float a = 0.f;
        for (int k = 0; k < 64; ++k)
            a += b1[k] * Wg0[k * 64 + c] + b2[k] * Wg0[(64 + k) * 64 + c];
        cvec[c] = a;
    }
}

// ---------- node features -> h0 [N,64] bf16 ----------
__global__ void node_embed(const int* __restrict__ type_ids,
                           const float* __restrict__ f0, const float* __restrict__ f1,
                           const float* __restrict__ f2, const float* __restrict__ f3,
                           const float* __restrict__ f4,
                           const float* __restrict__ M1, const float* __restrict__ M2,
                           const float* __restrict__ cvec,
                           unsigned short* __restrict__ hb, int n) {
    int i = blockIdx.x * (blockDim.x >> 6) + (threadIdx.x >> 6);
    int lane = threadIdx.x & 63;
    if (i >= n) return;
    int t = type_ids[i];
    float a = M1[t * 64 + lane] + cvec[lane];
    a += f0[i] * M2[0 * 64 + lane];
    a += f1[i] * M2[1 * 64 + lane];
    a += f2[i] * M2[2 * 64 + lane];
    a += f3[i] * M2[3 * 64 + lane];
    a += f4[i] * M2[4 * 64 + lane];
    hb[(size_t)i * 64 + lane] = f2bf(a);
}

// ---------- degree / CSR build ----------
__global__ void count_deg(const int* __restrict__ dst, int* __restrict__ deg, int e) {
    int i = blockIdx.x * blockDim.x + threadIdx.x;
    if (i < e) atomicAdd(&deg[dst[i]], 1);
}

// ---------- 3-phase scan (also emits dinv) ----------
#define SCAN_TILE 1024
__global__ void scan_local(const int* __restrict__ deg, int* __restrict__ loc,
                           int* __restrict__ tilesum, float* __restrict__ dinv, int n) {
    __shared__ int wsum[16];
    __shared__ int wexcl[16];
    const int tid = threadIdx.x;
    const int lane = tid & 63, w = tid >> 6;
    int i = blockIdx.x * SCAN_TILE + tid;
    int v = (i < n) ? deg[i] : 0;
    if (i < n) dinv[i] = rsqrtf((float)(v + 1));  // +1 self loop
    int incl = v;
#pragma unroll
    for (int ofs = 1; ofs < 64; ofs <<= 1) {
        int t = __shfl_up(incl, (unsigned)ofs, 64);
        if (lane >= ofs) incl += t;
    }
    if (lane == 63) wsum[w] = incl;
    __syncthreads();
    if (w == 0 && lane < 16) {
        int s = wsum[lane];
        int sc = s;
#pragma unroll
        for (int ofs = 1; ofs < 16; ofs <<= 1) {
            int t = __shfl_up(sc, (unsigned)ofs, 64);
            if (lane >= ofs) sc += t;
        }
        wexcl[lane] = sc - s;
        if (lane == 15) wsum[15] = sc;
    }
    __syncthreads();
    if (i < n) loc[i] = wexcl[w] + incl;
    if (tid == 0) tilesum[blockIdx.x] = wsum[15];
}

__global__ void scan_tiles(int* __restrict__ tilesum, int* __restrict__ tileoff, int nt) {
    int lane = threadIdx.x;
    int v = (lane < nt) ? tilesum[lane] : 0;
    int incl = v;
#pragma unroll
    for (int ofs = 1; ofs < 64; ofs <<= 1) {
        int t = __shfl_up(incl, (unsigned)ofs, 64);
        if (lane >= ofs) incl += t;
    }
    if (lane < nt) tileoff[lane] = incl - v;
}

__global__ void scan_add(const int* __restrict__ loc, const int* __restrict__ tileoff,
                         int* __restrict__ off, int* __restrict__ cursor, int n) {
    int i = blockIdx.x * blockDim.x + threadIdx.x;
    if (i >= n) return;
    int val = tileoff[i / SCAN_TILE] + loc[i];
    off[i + 1] = val;
    if (i + 1 < n) cursor[i + 1] = val;
    if (i == 0) { off[0] = 0; cursor[0] = 0; }
}

// ---------- fill CSR: ONE packed 8B store per edge ----------
__global__ void fill_csr(const int* __restrict__ src, const int* __restrict__ dst,
                         const float* __restrict__ dinv, int* __restrict__ cursor,
                         int2* __restrict__ csr, int e) {
    int i = blockIdx.x * blockDim.x + threadIdx.x;
    if (i >= e) return;
    int s = src[i], d = dst[i];
    int pos = atomicAdd(&cursor[d], 1);
    csr[pos] = make_int2(s, __float_as_int(dinv[s] * dinv[d]));
}

// ---------- conv gather (bf16 operand, MLP-batched): y fp32 ----------
__global__ void conv_gather(const unsigned short* __restrict__ hb,
                            const int* __restrict__ off, const int2* __restrict__ csr,
                            const float* __restrict__ dinv,
                            const float* __restrict__ bias, float* __restrict__ out, int n) {
    int i = blockIdx.x * (blockDim.x >> 6) + (threadIdx.x >> 6);
    int lane = threadIdx.x & 63;
    if (i >= n) return;
    int b = off[i], e = off[i + 1];
    float di = dinv[i];
    float acc = bf2f(hb[(size_t)i * 64 + lane]) * di * di;
    for (int k = b; k < e; k += GATHER_BATCH) {
        int   s[GATHER_BATCH];
        float w[GATHER_BATCH];
        float v[GATHER_BATCH];
#pragma unroll
        for (int u = 0; u < GATHER_BATCH; ++u) {
            int kk = k + u;
            bool ok = kk < e;
            int2 ent = ok ? csr[kk] : make_int2(i, 0);
            s[u] = ent.x;
            w[u] = ok ? __int_as_float(ent.y) : 0.f;
        }
#pragma unroll
        for (int u = 0; u < GATHER_BATCH; ++u) v[u] = bf2f(hb[(size_t)s[u] * 64 + lane]);
#pragma unroll
        for (int u = 0; u < GATHER_BATCH; ++u) acc += v[u] * w[u];
    }
    out[(size_t)i * 64 + lane] = acc + bias[lane];
}

// ---------- conv + relu + segmented mean-pool (layer 2) ----------
#define POOL_CHUNK 4
__global__ void conv_relu_pool(const unsigned short* __restrict__ hb,
                               const int* __restrict__ off, const int2* __restrict__ csr,
                               const float* __restrict__ dinv,
                               const float* __restrict__ bias, const int* __restrict__ batch,
                               float* __restrict__ pooled, int* __restrict__ cnt, int n) {
    int wave = blockIdx.x * (blockDim.x >> 6) + (threadIdx.x >> 6);
    int lane = threadIdx.x & 63;
    int start = wave * POOL_CHUNK;
    if (start >= n) return;
    int end = min(n, start + POOL_CHUNK);
    float bl = bias[lane];
    float accp = 0.f;
    int cur = batch[start];
    int cl = 0;
    for (int i = start; i < end; ++i) {
        int g = batch[i];
        if (g != cur) {  // wave-uniform (batch sorted)
            atomicAdd(&pooled[cur * 64 + lane], accp);
            if (lane == 0) atomicAdd(&cnt[cur], cl);
            accp = 0.f; cl = 0; cur = g;
        }
        int b = off[i], e = off[i + 1];
        float di = dinv[i];
        float a = bf2f(hb[(size_t)i * 64 + lane]) * di * di;
        for (int k = b; k < e; k += GATHER_BATCH) {
            int   s[GATHER_BATCH];
            float w[GATHER_BATCH];
            float v[GATHER_BATCH];
#pragma unroll
            for (int u = 0; u < GATHER_BATCH; ++u) {
                int kk = k + u;
                bool ok = kk < e;
                int2 ent = ok ? csr[kk] : make_int2(i, 0);
                s[u] = ent.x;
                w[u] = ok ? __int_as_float(ent.y) : 0.f;
            }
#pragma unroll
            for (int u = 0; u < GATHER_BATCH; ++u) v[u] = bf2f(hb[(size_t)s[u] * 64 + lane]);
#pragma unroll
            for (int u = 0; u < GATHER_BATCH; ++u) a += v[u] * w[u];
        }
        accp += fmaxf(a + bl, 0.f);
        ++cl;
    }
    atomicAdd(&pooled[cur * 64 + lane], accp);
    if (lane == 0) atomicAdd(&cnt[cur], cl);
}

// ---------- batchnorm stats: per-block partials ----------
__global__ void bn_stats(const float* __restrict__ y, float* __restrict__ partials, int n) {
    __shared__ float sh[4][128];
    int lane = threadIdx.x & 63;
    int w = threadIdx.x >> 6;
    int waves_per_blk = blockDim.x >> 6;
    float s = 0.f, ss = 0.f;
    for (int i = blockIdx.x * waves_per_blk + w; i < n; i += gridDim.x * waves_per_blk) {
        float v = y[(size_t)i * 64 + lane];
        s += v;
        ss += v * v;
    }
    sh[w][lane] = s;
    sh[w][64 + lane] = ss;
    __syncthreads();
    if (threadIdx.x < 128) {
        float a = sh[0][threadIdx.x] + sh[1][threadIdx.x] + sh[2][threadIdx.x] + sh[3][threadIdx.x];
        partials[blockIdx.x * 128 + threadIdx.x] = a;
    }
}

// parallel finalize: 1024 threads, 8 slices per channel, LDS tree
__global__ __launch_bounds__(1024) void bn_finalize(const float* __restrict__ partials, int nblk,
                            const float* __restrict__ gamma, const float* __restrict__ beta,
                            float* __restrict__ scsh, int n) {
    __shared__ float red[8][128];
    __shared__ float tot[128];
    int t = threadIdx.x;
    int ch = t & 127, sl = t >> 7;
    float a = 0.f;
#pragma unroll 8
    for (int b = sl; b < nblk; b += 8) a += partials[b * 128 + ch];
    red[sl][ch] = a;
    __syncthreads();
    if (t < 128) {
        float s = 0.f;
#pragma unroll
        for (int i = 0; i < 8; ++i) s += red[i][t];
        tot[t] = s;
    }
    __syncthreads();
    if (t < 64) {
        float mean = tot[t] / (float)n;
        float var = tot[64 + t] / (float)n - mean * mean;
        float sc = rsqrtf(var + 1e-5f) * gamma[t];
        scsh[t] = sc;
        scsh[64 + t] = beta[t] - mean * sc;
    }
}

// ---------- tiled bn+relu+GEMM: h(bf16) = relu(y*sc+sh) @ W ----------
// 256 threads, 128-node tile, 4x8 outputs per lane. kc loop NOT unrolled
// (R7: full unroll -> live-range explosion -> spills).
struct alignas(16) us8 { unsigned short v[8]; };
__global__ __launch_bounds__(256, 2) void bn_relu_gemm(const float* __restrict__ y,
                             const float* __restrict__ scsh, const float* __restrict__ W,
                             unsigned short* __restrict__ hb, int n) {
    __shared__ float4 yt4[128 * 16];
    __shared__ float4 wt4[64 * 16];
    float* wt = (float*)wt4;
    const int t = threadIdx.x;          // 256 threads
    const int base = blockIdx.x * 128;

    // stage W^T: read W[k][c0..c0+3] coalesced, scatter-transpose into wt[c][k]
    const float4* W4 = (const float4*)W;
#pragma unroll
    for (int i = 0; i < 4; ++i) {
        int g = t + 256 * i;
        int k = g >> 4;                 // W row = input channel
        int c0 = (g & 15) << 2;         // output-channel group
        float4 wv = W4[g];
        float wvf[4] = {wv.x, wv.y, wv.z, wv.w};
#pragma unroll
        for (int j = 0; j < 4; ++j) {
            int c = c0 + j;
            wt[c * 64 + (((k >> 2) ^ ((c >> 2) & 15)) << 2) + (k & 3)] = wvf[j];
        }
    }
    // stage yt = relu(y*sc+sh) (128x64 = 2048 float4)
    const float4* y4 = (const float4*)y;
#pragma unroll
    for (int i = 0; i < 8; ++i) {
        int g = t + 256 * i;
        int r = g >> 4, kc = g & 15;
        int row = base + r;
        float4 v = make_float4(0.f, 0.f, 0.f, 0.f);
        if (row < n) v = y4[(size_t)row * 16 + kc];
        int c0 = kc << 2;
        v.x = fmaxf(v.x * scsh[c0 + 0] + scsh[64 + c0 + 0], 0.f);
        v.y = fmaxf(v.y * scsh[c0 + 1] + scsh[64 + c0 + 1], 0.f);
        v.z = fmaxf(v.z * scsh[c0 + 2] + scsh[64 + c0 + 2], 0.f);
        v.w = fmaxf(v.w * scsh[c0 + 3] + scsh[64 + c0 + 3], 0.f);
        yt4[r * 16 + (kc ^ ((r >> 2) & 15))] = v;
    }
    __syncthreads();

    const int w = t >> 6;              // wave 0..3 -> nodes [w*32, w*32+32)
    const int lane = t & 63;
    const int ng = lane >> 3;          // 0..7
    const int cg = lane & 7;           // 0..7
    const int rl = w * 32 + ng * 4;    // local rows rl..rl+3
    const int c0 = cg * 8;             // channels c0..c0+7
    const int sa = (rl >> 2) & 15;     // same for all 4 rows
    float acc[4][8];
#pragma unroll
    for (int m = 0; m < 4; ++m)
#pragma unroll
        for (int j = 0; j < 8; ++j) acc[m][j] = 0.f;

#pragma unroll 1
    for (int kc = 0; kc < 16; ++kc) {
        float4 a[4];
#pragma unroll
        for (int m = 0; m < 4; ++m) a[m] = yt4[(rl + m) * 16 + (kc ^ sa)];
#pragma unroll
        for (int j = 0; j < 8; ++j) {
            int c = c0 + j;
            float4 b = wt4[c * 16 + (kc ^ ((c >> 2) & 15))];
#pragma unroll
            for (int m = 0; m < 4; ++m)
                acc[m][j] += a[m].x * b.x + a[m].y * b.y +
                             a[m].z * b.z + a[m].w * b.w;
        }
    }

#pragma unroll
    for (int m = 0; m < 4; ++m) {
        int row = base + rl + m;
        if (row < n) {
            us8 p;
#pragma unroll
            for (int j = 0; j < 8; ++j) p.v[j] = f2bf(acc[m][j]);
            *(us8*)&hb[(size_t)row * 64 + c0] = p;
        }
    }
}

// ---------- final: out[g] = (pooled[g]/cnt) @ Wout + bout ----------
__global__ void final_out(const float* __restrict__ pooled, const int* __restrict__ cnt,
                          const float* __restrict__ Wout, const float* __restrict__ bout,
                          float* __restrict__ out, int G) {
    int idx = blockIdx.x * blockDim.x + threadIdx.x;
    if (idx >= G * 4) return;
    int g = idx >> 2, o = idx & 3;
    float inv = 1.f / fmaxf((float)cnt[g], 1.f);
    float a = 0.f;
    for (int k = 0; k < 64; ++k) a += pooled[g * 64 + k] * Wout[k * 4 + o];
    out[idx] = a * inv + bout[o];
}

extern "C" void kernel_launch(void* const* d_in, const int* in_sizes, int n_in,
                              void* d_out, int out_size, void* d_ws, size_t ws_size,
                              hipStream_t stream) {
    const int N = in_sizes[0];
    const int E = in_sizes[6] / 2;
    const int T = in_sizes[8] / 64;
    const int G = out_size / 4;

    const int*   type_ids = (const int*)d_in[0];
    const float* fc   = (const float*)d_in[1];
    const float* fgm  = (const float*)d_in[2];
    const float* fpos = (const float*)d_in[3];
    const float* fr   = (const float*)d_in[4];
    const float* fvid = (const float*)d_in[5];
    const int*   ei   = (const int*)d_in[6];
    const int*   batch = (const int*)d_in[7];
    const float* W1 = (const float*)d_in[8];
    const float* b1 = (const float*)d_in[9];
    const float* W2 = (const float*)d_in[10];
    const float* b2 = (const float*)d_in[11];
    const float* Wg0 = (const float*)d_in[12];
    const float* bg0 = (const float*)d_in[13];
    const float* Wg1 = (const float*)d_in[14];
    const float* bg1 = (const float*)d_in[15];
    const float* Wg2 = (const float*)d_in[16];
    const float* bg2 = (const float*)d_in[17];
    const float* gam0 = (const float*)d_in[18];
    const float* bet0 = (const float*)d_in[19];
    const float* gam1 = (const float*)d_in[20];
    const float* bet1 = (const float*)d_in[21];
    const float* Wout = (const float*)d_in[22];
    const float* bout = (const float*)d_in[23];

    const int* e_src = ei;
    const int* e_dst = ei + E;

    // ---- workspace layout ----
    char* ws = (char*)d_ws;
    size_t o = 0;
    auto alloc = [&](size_t bytes) -> char* {
        char* p = ws + o;
        o += (bytes + 255) & ~(size_t)255;
        return p;
    };
    const int NBLK_BN = 256;
    const int NTILES = (N + SCAN_TILE - 1) / SCAN_TILE;
    unsigned short* hb = (unsigned short*)alloc((size_t)N * 64 * 2);
    float* y        = (float*)alloc((size_t)N * 64 * 4);
    int*   deg      = (int*)alloc((size_t)N * 4);
    float* dinv     = (float*)alloc((size_t)N * 4);
    int*   off      = (int*)alloc((size_t)(N + 1) * 4);
    int*   cursor   = (int*)alloc((size_t)N * 4);
    int*   loc      = (int*)alloc((size_t)N * 4);
    int*   tilesum  = (int*)alloc((size_t)NTILES * 4);
    int*   tileoff  = (int*)alloc((size_t)NTILES * 4);
    int2*  csr      = (int2*)alloc((size_t)E * 8);
    float* part0    = (float*)alloc((size_t)NBLK_BN * 128 * 4);
    float* part1    = (float*)alloc((size_t)NBLK_BN * 128 * 4);
    float* scsh0    = (float*)alloc(128 * 4);
    float* scsh1    = (float*)alloc(128 * 4);
    float* pooled   = (float*)alloc((size_t)G * 64 * 4);
    int*   cnt      = (int*)alloc((size_t)G * 4);
    float* M1       = (float*)alloc((size_t)T * 64 * 4);
    float* M2       = (float*)alloc(5 * 64 * 4);
    float* cvec     = (float*)alloc(64 * 4);
    (void)ws_size;

    hipMemsetAsync(deg, 0, (size_t)N * 4, stream);
    hipMemsetAsync(pooled, 0, (size_t)G * 64 * 4, stream);
    hipMemsetAsync(cnt, 0, (size_t)G * 4, stream);

    const int waves_per_blk = 4;                   // 256 threads
    const int nblk_nodes = (N + waves_per_blk - 1) / waves_per_blk;
    const int nblk_gemm = (N + 127) / 128;

    precompute_mats<<<1, 256, 0, stream>>>(W1, b1, W2, b2, Wg0, M1, M2, cvec, T);
    node_embed<<<nblk_nodes, 256, 0, stream>>>(type_ids, fc, fgm, fpos, fr, fvid, M1, M2, cvec, hb, N);

    count_deg<<<(E + 255) / 256, 256, 0, stream>>>(e_dst, deg, E);
    scan_local<<<NTILES, SCAN_TILE, 0, stream>>>(deg, loc, tilesum, dinv, N);
    scan_tiles<<<1, 64, 0, stream>>>(tilesum, tileoff, NTILES);
    scan_add<<<(N + 255) / 256, 256, 0, stream>>>(loc, tileoff, off, cursor, N);
    fill_csr<<<(E + 255) / 256, 256, 0, stream>>>(e_src, e_dst, dinv, cursor, csr, E);

    // layer 0
    conv_gather<<<nblk_nodes, 256, 0, stream>>>(hb, off, csr, dinv, bg0, y, N);
    bn_stats<<<NBLK_BN, 256, 0, stream>>>(y, part0, N);
    bn_finalize<<<1, 1024, 0, stream>>>(part0, NBLK_BN, gam0, bet0, scsh0, N);
    bn_relu_gemm<<<nblk_gemm, 256, 0, stream>>>(y, scsh0, Wg1, hb, N);

    // layer 1
    conv_gather<<<nblk_nodes, 256, 0, stream>>>(hb, off, csr, dinv, bg1, y, N);
    bn_stats<<<NBLK_BN, 256, 0, stream>>>(y, part1, N);
    bn_finalize<<<1, 1024, 0, stream>>>(part1, NBLK_BN, gam1, bet1, scsh1, N);
    bn_relu_gemm<<<nblk_gemm, 256, 0, stream>>>(y, scsh1, Wg2, hb, N);

    // layer 2: conv + relu + segmented mean-pool fused
    {
        int waves = (N + POOL_CHUNK - 1) / POOL_CHUNK;
        int blocks = (waves + waves_per_blk - 1) / waves_per_blk;
        conv_relu_pool<<<blocks, 256, 0, stream>>>(hb, off, csr, dinv, bg2, batch,
                                                   pooled, cnt, N);
    }

    final_out<<<(G * 4 + 255) / 256, 256, 0, stream>>>(pooled, cnt, Wout, bout, (float*)d_out, G);
}

// Round 11
// 350.715 us; speedup vs baseline: 1.0302x; 1.0302x over previous
//
#include <hip/hip_runtime.h>
#include <hip/hip_bf16.h>

// GCN: embed -> (conv -> bn -> relu) x2 -> conv(+relu+pool fused) -> linear
// H = 64.
// R10: latency-bound gather fixes: unpredicated int2 CSR batch loads (weight-
//      only masking, zero-padded tail), GATHER_BATCH=16 (2x MLP), 32-bit
//      gather addressing. (R7 no-unroll GEMM, R8 bf16 table, R9 int2 CSR kept.)

#define GATHER_BATCH 16

// bf16 helpers (bit ops; RTN-even)
__device__ __forceinline__ float bf2f(unsigned short u) {
    unsigned int x = ((unsigned int)u) << 16;
    return __int_as_float((int)x);
}
__device__ __forceinline__ unsigned short f2bf(float f) {
    unsigned int x = (unsigned int)__float_as_int(f);
    x += 0x7fffu + ((x >> 16) & 1u);
    return (unsigned short)(x >> 16);
}

// ---------- tiny precompute: fold one-hot/numeric linears through Wg0 ----------
__global__ void precompute_mats(const float* __restrict__ W1, const float* __restrict__ b1,
                                const float* __restrict__ W2, const float* __restrict__ b2,
                                const float* __restrict__ Wg0,
                                float* __restrict__ M1, float* __restrict__ M2,
                                float* __restrict__ cvec, int T) {
    int tid = threadIdx.x;
    for (int idx = tid; idx < T * 64; idx += blockDim.x) {
        int t = idx >> 6, c = idx & 63;
        float a = 0.f;
        for (int k = 0; k < 64; ++k) a += W1[t * 64 + k] * Wg0[k * 64 + c];
        M1[idx] = a;
    }
    for (int idx = tid; idx < 5 * 64; idx += blockDim.x) {
        int j = idx >> 6, c = idx & 63;
        float a = 0.f;
        for (int k = 0; k < 64; ++k) a += W2[j * 64 + k] * Wg0[(64 + k) * 64 + c];
        M2[idx] = a;
    }
    for (int c = tid; c < 64; c += blockDim.x) {
        float a = 0.f;
        for (int k = 0; k < 64; ++k)
            a += b1[k] * Wg0[k * 64 + c] + b2[k] * Wg0[(64 + k) * 64 + c];
        cvec[c] = a;
    }
}

// ---------- node features -> h0 [N,64] bf16 ----------
__global__ void node_embed(const int* __restrict__ type_ids,
                           const float* __restrict__ f0, const float* __restrict__ f1,
                           const float* __restrict__ f2, const float* __restrict__ f3,
                           const float* __restrict__ f4,
                           const float* __restrict__ M1, const float* __restrict__ M2,
                           const float* __restrict__ cvec,
                           unsigned short* __restrict__ hb, int n) {
    int i = blockIdx.x * (blockDim.x >> 6) + (threadIdx.x >> 6);
    int lane = threadIdx.x & 63;
    if (i >= n) return;
    int t = type_ids[i];
    float a = M1[t * 64 + lane] + cvec[lane];
    a += f0[i] * M2[0 * 64 + lane];
    a += f1[i] * M2[1 * 64 + lane];
    a += f2[i] * M2[2 * 64 + lane];
    a += f3[i] * M2[3 * 64 + lane];
    a += f4[i] * M2[4 * 64 + lane];
    hb[((unsigned)i << 6) | lane] = f2bf(a);
}

// ---------- degree / CSR build ----------
__global__ void count_deg(const int* __restrict__ dst, int* __restrict__ deg, int e) {
    int i = blockIdx.x * blockDim.x + threadIdx.x;
    if (i < e) atomicAdd(&deg[dst[i]], 1);
}

// ---------- 3-phase scan (also emits dinv) ----------
#define SCAN_TILE 1024
__global__ void scan_local(const int* __restrict__ deg, int* __restrict__ loc,
                           int* __restrict__ tilesum, float* __restrict__ dinv, int n) {
    __shared__ int wsum[16];
    __shared__ int wexcl[16];
    const int tid = threadIdx.x;
    const int lane = tid & 63, w = tid >> 6;
    int i = blockIdx.x * SCAN_TILE + tid;
    int v = (i < n) ? deg[i] : 0;
    if (i < n) dinv[i] = rsqrtf((float)(v + 1));  // +1 self loop
    int incl = v;
#pragma unroll
    for (int ofs = 1; ofs < 64; ofs <<= 1) {
        int t = __shfl_up(incl, (unsigned)ofs, 64);
        if (lane >= ofs) incl += t;
    }
    if (lane == 63) wsum[w] = incl;
    __syncthreads();
    if (w == 0 && lane < 16) {
        int s = wsum[lane];
        int sc = s;
#pragma unroll
        for (int ofs = 1; ofs < 16; ofs <<= 1) {
            int t = __shfl_up(sc, (unsigned)ofs, 64);
            if (lane >= ofs) sc += t;
        }
        wexcl[lane] = sc - s;
        if (lane == 15) wsum[15] = sc;
    }
    __syncthreads();
    if (i < n) loc[i] = wexcl[w] + incl;
    if (tid == 0) tilesum[blockIdx.x] = wsum[15];
}

__global__ void scan_tiles(int* __restrict__ tilesum, int* __restrict__ tileoff, int nt) {
    int lane = threadIdx.x;
    int v = (lane < nt) ? tilesum[lane] : 0;
    int incl = v;
#pragma unroll
    for (int ofs = 1; ofs < 64; ofs <<= 1) {
        int t = __shfl_up(incl, (unsigned)ofs, 64);
        if (lane >= ofs) incl += t;
    }
    if (lane < nt) tileoff[lane] = incl - v;
}

__global__ void scan_add(const int* __restrict__ loc, const int* __restrict__ tileoff,
                         int* __restrict__ off, int* __restrict__ cursor, int n) {
    int i = blockIdx.x * blockDim.x + threadIdx.x;
    if (i >= n) return;
    int val = tileoff[i / SCAN_TILE] + loc[i];
    off[i + 1] = val;
    if (i + 1 < n) cursor[i + 1] = val;
    if (i == 0) { off[0] = 0; cursor[0] = 0; }
}

// ---------- fill CSR: ONE packed 8B store per edge ----------
__global__ void fill_csr(const int* __restrict__ src, const int* __restrict__ dst,
                         const float* __restrict__ dinv, int* __restrict__ cursor,
                         int2* __restrict__ csr, int e) {
    int i = blockIdx.x * blockDim.x + threadIdx.x;
    if (i >= e) return;
    int s = src[i], d = dst[i];
    int pos = atomicAdd(&cursor[d], 1);
    csr[pos] = make_int2(s, __float_as_int(dinv[s] * dinv[d]));
}

// ---------- conv gather: unpredicated batch loads, weight-only masking ----------
__global__ void conv_gather(const unsigned short* __restrict__ hb,
                            const int* __restrict__ off, const int2* __restrict__ csr,
                            const float* __restrict__ dinv,
                            const float* __restrict__ bias, float* __restrict__ out, int n) {
    int i = blockIdx.x * (blockDim.x >> 6) + (threadIdx.x >> 6);
    int lane = threadIdx.x & 63;
    if (i >= n) return;
    int b = off[i], e = off[i + 1];
    float di = dinv[i];
    float acc = bf2f(hb[((unsigned)i << 6) | lane]) * di * di;
    for (int k = b; k < e; k += GATHER_BATCH) {
        int   s[GATHER_BATCH];
        float w[GATHER_BATCH];
        float v[GATHER_BATCH];
#pragma unroll
        for (int u = 0; u < GATHER_BATCH; ++u) {
            int2 ent = csr[k + u];          // unpredicated (tail zero-padded)
            s[u] = ent.x;
            w[u] = (k + u < e) ? __int_as_float(ent.y) : 0.f;  // scalar-cond mask
        }
#pragma unroll
        for (int u = 0; u < GATHER_BATCH; ++u)
            v[u] = bf2f(hb[((unsigned)s[u] << 6) | lane]);
#pragma unroll
        for (int u = 0; u < GATHER_BATCH; ++u) acc += v[u] * w[u];
    }
    out[((size_t)i << 6) | lane] = acc + bias[lane];
}

// ---------- conv + relu + segmented mean-pool (layer 2) ----------
#define POOL_CHUNK 4
__global__ void conv_relu_pool(const unsigned short* __restrict__ hb,
                               const int* __restrict__ off, const int2* __restrict__ csr,
                               const float* __restrict__ dinv,
                               const float* __restrict__ bias, const int* __restrict__ batch,
                               float* __restrict__ pooled, int* __restrict__ cnt, int n) {
    int wave = blockIdx.x * (blockDim.x >> 6) + (threadIdx.x >> 6);
    int lane = threadIdx.x & 63;
    int start = wave * POOL_CHUNK;
    if (start >= n) return;
    int end = min(n, start + POOL_CHUNK);
    float bl = bias[lane];
    float accp = 0.f;
    int cur = batch[start];
    int cl = 0;
    for (int i = start; i < end; ++i) {
        int g = batch[i];
        if (g != cur) {  // wave-uniform (batch sorted)
            atomicAdd(&pooled[cur * 64 + lane], accp);
            if (lane == 0) atomicAdd(&cnt[cur], cl);
            accp = 0.f; cl = 0; cur = g;
        }
        int b = off[i], e = off[i + 1];
        float di = dinv[i];
        float a = bf2f(hb[((unsigned)i << 6) | lane]) * di * di;
        for (int k = b; k < e; k += GATHER_BATCH) {
            int   s[GATHER_BATCH];
            float w[GATHER_BATCH];
            float v[GATHER_BATCH];
#pragma unroll
            for (int u = 0; u < GATHER_BATCH; ++u) {
                int2 ent = csr[k + u];      // unpredicated (tail zero-padded)
                s[u] = ent.x;
                w[u] = (k + u < e) ? __int_as_float(ent.y) : 0.f;
            }
#pragma unroll
            for (int u = 0; u < GATHER_BATCH; ++u)
                v[u] = bf2f(hb[((unsigned)s[u] << 6) | lane]);
#pragma unroll
            for (int u = 0; u < GATHER_BATCH; ++u) a += v[u] * w[u];
        }
        accp += fmaxf(a + bl, 0.f);
        ++cl;
    }
    atomicAdd(&pooled[cur * 64 + lane], accp);
    if (lane == 0) atomicAdd(&cnt[cur], cl);
}

// ---------- batchnorm stats: per-block partials ----------
__global__ void bn_stats(const float* __restrict__ y, float* __restrict__ partials, int n) {
    __shared__ float sh[4][128];
    int lane = threadIdx.x & 63;
    int w = threadIdx.x >> 6;
    int waves_per_blk = blockDim.x >> 6;
    float s = 0.f, ss = 0.f;
    for (int i = blockIdx.x * waves_per_blk + w; i < n; i += gridDim.x * waves_per_blk) {
        float v = y[((size_t)i << 6) | lane];
        s += v;
        ss += v * v;
    }
    sh[w][lane] = s;
    sh[w][64 + lane] = ss;
    __syncthreads();
    if (threadIdx.x < 128) {
        float a = sh[0][threadIdx.x] + sh[1][threadIdx.x] + sh[2][threadIdx.x] + sh[3][threadIdx.x];
        partials[blockIdx.x * 128 + threadIdx.x] = a;
    }
}

// parallel finalize: 1024 threads, 8 slices per channel, LDS tree
__global__ __launch_bounds__(1024) void bn_finalize(const float* __restrict__ partials, int nblk,
                            const float* __restrict__ gamma, const float* __restrict__ beta,
                            float* __restrict__ scsh, int n) {
    __shared__ float red[8][128];
    __shared__ float tot[128];
    int t = threadIdx.x;
    int ch = t & 127, sl = t >> 7;
    float a = 0.f;
#pragma unroll 8
    for (int b = sl; b < nblk; b += 8) a += partials[b * 128 + ch];
    red[sl][ch] = a;
    __syncthreads();
    if (t < 128) {
        float s = 0.f;
#pragma unroll
        for (int i = 0; i < 8; ++i) s += red[i][t];
        tot[t] = s;
    }
    __syncthreads();
    if (t < 64) {
        float mean = tot[t] / (float)n;
        float var = tot[64 + t] / (float)n - mean * mean;
        float sc = rsqrtf(var + 1e-5f) * gamma[t];
        scsh[t] = sc;
        scsh[64 + t] = beta[t] - mean * sc;
    }
}

// ---------- tiled bn+relu+GEMM: h(bf16) = relu(y*sc+sh) @ W ----------
// 256 threads, 128-node tile, 4x8 outputs per lane. kc loop NOT unrolled
// (R7: full unroll -> live-range explosion -> spills).
struct alignas(16) us8 { unsigned short v[8]; };
__global__ __launch_bounds__(256, 2) void bn_relu_gemm(const float* __restrict__ y,
                             const float* __restrict__ scsh, const float* __restrict__ W,
                             unsigned short* __restrict__ hb, int n) {
    __shared__ float4 yt4[128 * 16];
    __shared__ float4 wt4[64 * 16];
    float* wt = (float*)wt4;
    const int t = threadIdx.x;          // 256 threads
    const int base = blockIdx.x * 128;

    // stage W^T: read W[k][c0..c0+3] coalesced, scatter-transpose into wt[c][k]
    const float4* W4 = (const float4*)W;
#pragma unroll
    for (int i = 0; i < 4; ++i) {
        int g = t + 256 * i;
        int k = g >> 4;                 // W row = input channel
        int c0 = (g & 15) << 2;         // output-channel group
        float4 wv = W4[g];
        float wvf[4] = {wv.x, wv.y, wv.z, wv.w};
#pragma unroll
        for (int j = 0; j < 4; ++j) {
            int c = c0 + j;
            wt[c * 64 + (((k >> 2) ^ ((c >> 2) & 15)) << 2) + (k & 3)] = wvf[j];
        }
    }
    // stage yt = relu(y*sc+sh) (128x64 = 2048 float4)
    const float4* y4 = (const float4*)y;
#pragma unroll
    for (int i = 0; i < 8; ++i) {
        int g = t + 256 * i;
        int r = g >> 4, kc = g & 15;
        int row = base + r;
        float4 v = make_float4(0.f, 0.f, 0.f, 0.f);
        if (row < n) v = y4[(size_t)row * 16 + kc];
        int c0 = kc << 2;
        v.x = fmaxf(v.x * scsh[c0 + 0] + scsh[64 + c0 + 0], 0.f);
        v.y = fmaxf(v.y * scsh[c0 + 1] + scsh[64 + c0 + 1], 0.f);
        v.z = fmaxf(v.z * scsh[c0 + 2] + scsh[64 + c0 + 2], 0.f);
        v.w = fmaxf(v.w * scsh[c0 + 3] + scsh[64 + c0 + 3], 0.f);
        yt4[r * 16 + (kc ^ ((r >> 2) & 15))] = v;
    }
    __syncthreads();

    const int w = t >> 6;              // wave 0..3 -> nodes [w*32, w*32+32)
    const int lane = t & 63;
    const int ng = lane >> 3;          // 0..7
    const int cg = lane & 7;           // 0..7
    const int rl = w * 32 + ng * 4;    // local rows rl..rl+3
    const int c0 = cg * 8;             // channels c0..c0+7
    const int sa = (rl >> 2) & 15;     // same for all 4 rows
    float acc[4][8];
#pragma unroll
    for (int m = 0; m < 4; ++m)
#pragma unroll
        for (int j = 0; j < 8; ++j) acc[m][j] = 0.f;

#pragma unroll 1
    for (int kc = 0; kc < 16; ++kc) {
        float4 a[4];
#pragma unroll
        for (int m = 0; m < 4; ++m) a[m] = yt4[(rl + m) * 16 + (kc ^ sa)];
#pragma unroll
        for (int j = 0; j < 8; ++j) {
            int c = c0 + j;
            float4 b = wt4[c * 16 + (kc ^ ((c >> 2) & 15))];
#pragma unroll
            for (int m = 0; m < 4; ++m)
                acc[m][j] += a[m].x * b.x + a[m].y * b.y +
                             a[m].z * b.z + a[m].w * b.w;
        }
    }

#pragma unroll
    for (int m = 0; m < 4; ++m) {
        int row = base + rl + m;
        if (row < n) {
            us8 p;
#pragma unroll
            for (int j = 0; j < 8; ++j) p.v[j] = f2bf(acc[m][j]);
            *(us8*)&hb[((size_t)row << 6) | c0] = p;
        }
    }
}

// ---------- final: out[g] = (pooled[g]/cnt) @ Wout + bout ----------
__global__ void final_out(const float* __restrict__ pooled, const int* __restrict__ cnt,
                          const float* __restrict__ Wout, const float* __restrict__ bout,
                          float* __restrict__ out, int G) {
    int idx = blockIdx.x * blockDim.x + threadIdx.x;
    if (idx >= G * 4) return;
    int g = idx >> 2, o = idx & 3;
    float inv = 1.f / fmaxf((float)cnt[g], 1.f);
    float a = 0.f;
    for (int k = 0; k < 64; ++k) a += pooled[g * 64 + k] * Wout[k * 4 + o];
    out[idx] = a * inv + bout[o];
}

extern "C" void kernel_launch(void* const* d_in, const int* in_sizes, int n_in,
                              void* d_out, int out_size, void* d_ws, size_t ws_size,
                              hipStream_t stream) {
    const int N = in_sizes[0];
    const int E = in_sizes[6] / 2;
    const int T = in_sizes[8] / 64;
    const int G = out_size / 4;

    const int*   type_ids = (const int*)d_in[0];
    const float* fc   = (const float*)d_in[1];
    const float* fgm  = (const float*)d_in[2];
    const float* fpos = (const float*)d_in[3];
    const float* fr   = (const float*)d_in[4];
    const float* fvid = (const float*)d_in[5];
    const int*   ei   = (const int*)d_in[6];
    const int*   batch = (const int*)d_in[7];
    const float* W1 = (const float*)d_in[8];
    const float* b1 = (const float*)d_in[9];
    const float* W2 = (const float*)d_in[10];
    const float* b2 = (const float*)d_in[11];
    const float* Wg0 = (const float*)d_in[12];
    const float* bg0 = (const float*)d_in[13];
    const float* Wg1 = (const float*)d_in[14];
    const float* bg1 = (const float*)d_in[15];
    const float* Wg2 = (const float*)d_in[16];
    const float* bg2 = (const float*)d_in[17];
    const float* gam0 = (const float*)d_in[18];
    const float* bet0 = (const float*)d_in[19];
    const float* gam1 = (const float*)d_in[20];
    const float* bet1 = (const float*)d_in[21];
    const float* Wout = (const float*)d_in[22];
    const float* bout = (const float*)d_in[23];

    const int* e_src = ei;
    const int* e_dst = ei + E;

    // ---- workspace layout ----
    char* ws = (char*)d_ws;
    size_t o = 0;
    auto alloc = [&](size_t bytes) -> char* {
        char* p = ws + o;
        o += (bytes + 255) & ~(size_t)255;
        return p;
    };
    const int NBLK_BN = 256;
    const int NTILES = (N + SCAN_TILE - 1) / SCAN_TILE;
    unsigned short* hb = (unsigned short*)alloc((size_t)N * 64 * 2);
    float* y        = (float*)alloc((size_t)N * 64 * 4);
    int*   deg      = (int*)alloc((size_t)N * 4);
    float* dinv     = (float*)alloc((size_t)N * 4);
    int*   off      = (int*)alloc((size_t)(N + 1) * 4);
    int*   cursor   = (int*)alloc((size_t)N * 4);
    int*   loc      = (int*)alloc((size_t)N * 4);
    int*   tilesum  = (int*)alloc((size_t)NTILES * 4);
    int*   tileoff  = (int*)alloc((size_t)NTILES * 4);
    int2*  csr      = (int2*)alloc(((size_t)E + GATHER_BATCH) * 8);
    float* part0    = (float*)alloc((size_t)NBLK_BN * 128 * 4);
    float* part1    = (float*)alloc((size_t)NBLK_BN * 128 * 4);
    float* scsh0    = (float*)alloc(128 * 4);
    float* scsh1    = (float*)alloc(128 * 4);
    float* pooled   = (float*)alloc((size_t)G * 64 * 4);
    int*   cnt      = (int*)alloc((size_t)G * 4);
    float* M1       = (float*)alloc((size_t)T * 64 * 4);
    float* M2       = (float*)alloc(5 * 64 * 4);
    float* cvec     = (float*)alloc(64 * 4);
    (void)ws_size;

    hipMemsetAsync(deg, 0, (size_t)N * 4, stream);
    hipMemsetAsync(csr + E, 0, (size_t)GATHER_BATCH * 8, stream);  // zero pad tail
    hipMemsetAsync(pooled, 0, (size_t)G * 64 * 4, stream);
    hipMemsetAsync(cnt, 0, (size_t)G * 4, stream);

    const int waves_per_blk = 4;                   // 256 threads
    const int nblk_nodes = (N + waves_per_blk - 1) / waves_per_blk;
    const int nblk_gemm = (N + 127) / 128;

    precompute_mats<<<1, 256, 0, stream>>>(W1, b1, W2, b2, Wg0, M1, M2, cvec, T);
    node_embed<<<nblk_nodes, 256, 0, stream>>>(type_ids, fc, fgm, fpos, fr, fvid, M1, M2, cvec, hb, N);

    count_deg<<<(E + 255) / 256, 256, 0, stream>>>(e_dst, deg, E);
    scan_local<<<NTILES, SCAN_TILE, 0, stream>>>(deg, loc, tilesum, dinv, N);
    scan_tiles<<<1, 64, 0, stream>>>(tilesum, tileoff, NTILES);
    scan_add<<<(N + 255) / 256, 256, 0, stream>>>(loc, tileoff, off, cursor, N);
    fill_csr<<<(E + 255) / 256, 256, 0, stream>>>(e_src, e_dst, dinv, cursor, csr, E);

    // layer 0
    conv_gather<<<nblk_nodes, 256, 0, stream>>>(hb, off, csr, dinv, bg0, y, N);
    bn_stats<<<NBLK_BN, 256, 0, stream>>>(y, part0, N);
    bn_finalize<<<1, 1024, 0, stream>>>(part0, NBLK_BN, gam0, bet0, scsh0, N);
    bn_relu_gemm<<<nblk_gemm, 256, 0, stream>>>(y, scsh0, Wg1, hb, N);

    // layer 1
    conv_gather<<<nblk_nodes, 256, 0, stream>>>(hb, off, csr, dinv, bg1, y, N);
    bn_stats<<<NBLK_BN, 256, 0, stream>>>(y, part1, N);
    bn_finalize<<<1, 1024, 0, stream>>>(part1, NBLK_BN, gam1, bet1, scsh1, N);
    bn_relu_gemm<<<nblk_gemm, 256, 0, stream>>>(y, scsh1, Wg2, hb, N);

    // layer 2: conv + relu + segmented mean-pool fused
    {
        int waves = (N + POOL_CHUNK - 1) / POOL_CHUNK;
        int blocks = (waves + waves_per_blk - 1) / waves_per_blk;
        conv_relu_pool<<<blocks, 256, 0, stream>>>(hb, off, csr, dinv, bg2, batch,
                                                   pooled, cnt, N);
    }

    final_out<<<(G * 4 + 255) / 256, 256, 0, stream>>>(pooled, cnt, Wout, bout, (float*)d_out, G);
}

// Round 12
// 306.273 us; speedup vs baseline: 1.1796x; 1.1451x over previous
//
#include <hip/hip_runtime.h>
#include <hip/hip_bf16.h>

// GCN: embed -> (conv -> bn -> relu) x2 -> conv(+relu+pool fused) -> linear
// H = 64.
// R11: conv gather restructured to 8-lanes-per-edge x uint4 (16B/lane):
//      one wave VMEM instruction fetches 8 full edge rows (1KB) vs 1 edge
//      (128B) in the lane-per-channel layout. Self-loop = logical edge 0,
//      CSR front+tail padded for unpredicated loads, 2x unrolled batches,
//      __shfl_xor tree reduce. (R7 no-unroll GEMM, R8 bf16, R9 int2 kept.)

// bf16 helpers
__device__ __forceinline__ float bf2f(unsigned short u) {
    unsigned int x = ((unsigned int)u) << 16;
    return __int_as_float((int)x);
}
__device__ __forceinline__ unsigned short f2bf(float f) {
    unsigned int x = (unsigned int)__float_as_int(f);
    x += 0x7fffu + ((x >> 16) & 1u);
    return (unsigned short)(x >> 16);
}

// ---------- tiny precompute: fold one-hot/numeric linears through Wg0 ----------
__global__ void precompute_mats(const float* __restrict__ W1, const float* __restrict__ b1,
                                const float* __restrict__ W2, const float* __restrict__ b2,
                                const float* __restrict__ Wg0,
                                float* __restrict__ M1, float* __restrict__ M2,
                                float* __restrict__ cvec, int T) {
    int tid = threadIdx.x;
    for (int idx = tid; idx < T * 64; idx += blockDim.x) {
        int t = idx >> 6, c = idx & 63;
        float a = 0.f;
        for (int k = 0; k < 64; ++k) a += W1[t * 64 + k] * Wg0[k * 64 + c];
        M1[idx] = a;
    }
    for (int idx = tid; idx < 5 * 64; idx += blockDim.x) {
        int j = idx >> 6, c = idx & 63;
        float a = 0.f;
        for (int k = 0; k < 64; ++k) a += W2[j * 64 + k] * Wg0[(64 + k) * 64 + c];
        M2[idx] = a;
    }
    for (int c = tid; c < 64; c += blockDim.x) {
        float a = 0.f;
        for (int k = 0; k < 64; ++k)
            a += b1[k] * Wg0[k * 64 + c] + b2[k] * Wg0[(64 + k) * 64 + c];
        cvec[c] = a;
    }
}

// ---------- node features -> h0 [N,64] bf16 ----------
__global__ void node_embed(const int* __restrict__ type_ids,
                           const float* __restrict__ f0, const float* __restrict__ f1,
                           const float* __restrict__ f2, const float* __restrict__ f3,
                           const float* __restrict__ f4,
                           const float* __restrict__ M1, const float* __restrict__ M2,
                           const float* __restrict__ cvec,
                           unsigned short* __restrict__ hb, int n) {
    int i = blockIdx.x * (blockDim.x >> 6) + (threadIdx.x >> 6);
    int lane = threadIdx.x & 63;
    if (i >= n) return;
    int t = type_ids[i];
    float a = M1[t * 64 + lane] + cvec[lane];
    a += f0[i] * M2[0 * 64 + lane];
    a += f1[i] * M2[1 * 64 + lane];
    a += f2[i] * M2[2 * 64 + lane];
    a += f3[i] * M2[3 * 64 + lane];
    a += f4[i] * M2[4 * 64 + lane];
    hb[((unsigned)i << 6) | lane] = f2bf(a);
}

// ---------- degree / CSR build ----------
__global__ void count_deg(const int* __restrict__ dst, int* __restrict__ deg, int e) {
    int i = blockIdx.x * blockDim.x + threadIdx.x;
    if (i < e) atomicAdd(&deg[dst[i]], 1);
}

// ---------- 3-phase scan (also emits dinv) ----------
#define SCAN_TILE 1024
__global__ void scan_local(const int* __restrict__ deg, int* __restrict__ loc,
                           int* __restrict__ tilesum, float* __restrict__ dinv, int n) {
    __shared__ int wsum[16];
    __shared__ int wexcl[16];
    const int tid = threadIdx.x;
    const int lane = tid & 63, w = tid >> 6;
    int i = blockIdx.x * SCAN_TILE + tid;
    int v = (i < n) ? deg[i] : 0;
    if (i < n) dinv[i] = rsqrtf((float)(v + 1));  // +1 self loop
    int incl = v;
#pragma unroll
    for (int ofs = 1; ofs < 64; ofs <<= 1) {
        int t = __shfl_up(incl, (unsigned)ofs, 64);
        if (lane >= ofs) incl += t;
    }
    if (lane == 63) wsum[w] = incl;
    __syncthreads();
    if (w == 0 && lane < 16) {
        int s = wsum[lane];
        int sc = s;
#pragma unroll
        for (int ofs = 1; ofs < 16; ofs <<= 1) {
            int t = __shfl_up(sc, (unsigned)ofs, 64);
            if (lane >= ofs) sc += t;
        }
        wexcl[lane] = sc - s;
        if (lane == 15) wsum[15] = sc;
    }
    __syncthreads();
    if (i < n) loc[i] = wexcl[w] + incl;
    if (tid == 0) tilesum[blockIdx.x] = wsum[15];
}

__global__ void scan_tiles(int* __restrict__ tilesum, int* __restrict__ tileoff, int nt) {
    int lane = threadIdx.x;
    int v = (lane < nt) ? tilesum[lane] : 0;
    int incl = v;
#pragma unroll
    for (int ofs = 1; ofs < 64; ofs <<= 1) {
        int t = __shfl_up(incl, (unsigned)ofs, 64);
        if (lane >= ofs) incl += t;
    }
    if (lane < nt) tileoff[lane] = incl - v;
}

__global__ void scan_add(const int* __restrict__ loc, const int* __restrict__ tileoff,
                         int* __restrict__ off, int* __restrict__ cursor, int n) {
    int i = blockIdx.x * blockDim.x + threadIdx.x;
    if (i >= n) return;
    int val = tileoff[i / SCAN_TILE] + loc[i];
    off[i + 1] = val;
    if (i + 1 < n) cursor[i + 1] = val;
    if (i == 0) { off[0] = 0; cursor[0] = 0; }
}

// ---------- fill CSR: ONE packed 8B store per edge ----------
__global__ void fill_csr(const int* __restrict__ src, const int* __restrict__ dst,
                         const float* __restrict__ dinv, int* __restrict__ cursor,
                         int2* __restrict__ csr, int e) {
    int i = blockIdx.x * blockDim.x + threadIdx.x;
    if (i >= e) return;
    int s = src[i], d = dst[i];
    int pos = atomicAdd(&cursor[d], 1);
    csr[pos] = make_int2(s, __float_as_int(dinv[s] * dinv[d]));
}

// ---------- conv gather: 8 lanes/edge, uint4 rows, shfl-tree reduce ----------
// lane = eg*8+cc: edge slot eg (0..7), channel chunk cc (8 bf16 via uint4).
// Logical entry j: j==0 self (w=dinv^2), j in [1,deg] edge csr[b+j-1].
// csr has front pad (index -1 valid) and >=16 tail pad entries (zeros).
__device__ __forceinline__ void gather_fma(float acc[8], uint4 v, float w) {
    acc[0] += __uint_as_float(v.x << 16) * w;
    acc[1] += __uint_as_float(v.x & 0xffff0000u) * w;
    acc[2] += __uint_as_float(v.y << 16) * w;
    acc[3] += __uint_as_float(v.y & 0xffff0000u) * w;
    acc[4] += __uint_as_float(v.z << 16) * w;
    acc[5] += __uint_as_float(v.z & 0xffff0000u) * w;
    acc[6] += __uint_as_float(v.w << 16) * w;
    acc[7] += __uint_as_float(v.w & 0xffff0000u) * w;
}

__device__ __forceinline__ void node_aggregate(float acc[8],
                                               const unsigned short* __restrict__ hb,
                                               const int2* __restrict__ csr,
                                               int i, int b, int deg, float ws,
                                               int eg, int cc) {
#pragma unroll
    for (int q = 0; q < 8; ++q) acc[q] = 0.f;
    int nb = (deg + 8) >> 3;  // ceil((deg+1)/8)
#pragma unroll 1
    for (int t = 0; t < nb; t += 2) {
        int j = (t << 3) + eg;
        int j2 = j + 8;
        int2 entA = csr[b + j - 1];
        int2 entB = csr[b + j2 - 1];
        int sA = (j == 0) ? i : entA.x;
        float wA = (j == 0) ? ws : ((j <= deg) ? __int_as_float(entA.y) : 0.f);
        int sB = entB.x;
        float wB = (j2 <= deg) ? __int_as_float(entB.y) : 0.f;
        uint4 vA = *(const uint4*)&hb[((unsigned)sA << 6) + (cc << 3)];
        uint4 vB = *(const uint4*)&hb[((unsigned)sB << 6) + (cc << 3)];
        gather_fma(acc, vA, wA);
        gather_fma(acc, vB, wB);
    }
    // reduce across the 8 edge-groups (lane bits 3..5)
#pragma unroll
    for (int q = 0; q < 8; ++q) {
        acc[q] += __shfl_xor(acc[q], 8, 64);
        acc[q] += __shfl_xor(acc[q], 16, 64);
        acc[q] += __shfl_xor(acc[q], 32, 64);
    }
}

__global__ void conv_gather(const unsigned short* __restrict__ hb,
                            const int* __restrict__ off, const int2* __restrict__ csr,
                            const float* __restrict__ dinv,
                            const float* __restrict__ bias, float* __restrict__ out, int n) {
    int i = blockIdx.x * (blockDim.x >> 6) + (threadIdx.x >> 6);
    if (i >= n) return;
    const int lane = threadIdx.x & 63;
    const int eg = lane >> 3, cc = lane & 7;
    int b = off[i], e = off[i + 1];
    float di = dinv[i];
    float acc[8];
    node_aggregate(acc, hb, csr, i, b, e - b, di * di, eg, cc);
    if (eg == 0) {
        const float4* b4 = (const float4*)bias;
        float4 bb0 = b4[cc * 2], bb1 = b4[cc * 2 + 1];
        float4 o0 = make_float4(acc[0] + bb0.x, acc[1] + bb0.y, acc[2] + bb0.z, acc[3] + bb0.w);
        float4 o1 = make_float4(acc[4] + bb1.x, acc[5] + bb1.y, acc[6] + bb1.z, acc[7] + bb1.w);
        float4* o = (float4*)&out[((size_t)i << 6) + (cc << 3)];
        o[0] = o0;
        o[1] = o1;
    }
}

// ---------- conv + relu + segmented mean-pool (layer 2) ----------
#define POOL_CHUNK 4
__global__ void conv_relu_pool(const unsigned short* __restrict__ hb,
                               const int* __restrict__ off, const int2* __restrict__ csr,
                               const float* __restrict__ dinv,
                               const float* __restrict__ bias, const int* __restrict__ batch,
                               float* __restrict__ pooled, int* __restrict__ cnt, int n) {
    int wave = blockIdx.x * (blockDim.x >> 6) + (threadIdx.x >> 6);
    const int lane = threadIdx.x & 63;
    const int eg = lane >> 3, cc = lane & 7;
    int start = wave * POOL_CHUNK;
    if (start >= n) return;
    int end = min(n, start + POOL_CHUNK);
    const float4* b4 = (const float4*)bias;
    float4 bb0 = b4[cc * 2], bb1 = b4[cc * 2 + 1];
    float bl[8] = {bb0.x, bb0.y, bb0.z, bb0.w, bb1.x, bb1.y, bb1.z, bb1.w};
    float accp[8];
#pragma unroll
    for (int q = 0; q < 8; ++q) accp[q] = 0.f;
    int cur = batch[start];
    int cl = 0;
    for (int i = start; i < end; ++i) {
        int g = batch[i];
        if (g != cur) {  // wave-uniform (batch sorted)
            if (eg == 0) {
                float* p = &pooled[cur * 64 + (cc << 3)];
#pragma unroll
                for (int q = 0; q < 8; ++q) atomicAdd(&p[q], accp[q]);
            }
            if (lane == 0) atomicAdd(&cnt[cur], cl);
#pragma unroll
            for (int q = 0; q < 8; ++q) accp[q] = 0.f;
            cl = 0; cur = g;
        }
        int b = off[i], e = off[i + 1];
        float di = dinv[i];
        float acc[8];
        node_aggregate(acc, hb, csr, i, b, e - b, di * di, eg, cc);
#pragma unroll
        for (int q = 0; q < 8; ++q) accp[q] += fmaxf(acc[q] + bl[q], 0.f);
        ++cl;
    }
    if (eg == 0) {
        float* p = &pooled[cur * 64 + (cc << 3)];
#pragma unroll
        for (int q = 0; q < 8; ++q) atomicAdd(&p[q], accp[q]);
    }
    if (lane == 0) atomicAdd(&cnt[cur], cl);
}

// ---------- batchnorm stats: per-block partials ----------
__global__ void bn_stats(const float* __restrict__ y, float* __restrict__ partials, int n) {
    __shared__ float sh[4][128];
    int lane = threadIdx.x & 63;
    int w = threadIdx.x >> 6;
    int waves_per_blk = blockDim.x >> 6;
    float s = 0.f, ss = 0.f;
    for (int i = blockIdx.x * waves_per_blk + w; i < n; i += gridDim.x * waves_per_blk) {
        float v = y[((size_t)i << 6) | lane];
        s += v;
        ss += v * v;
    }
    sh[w][lane] = s;
    sh[w][64 + lane] = ss;
    __syncthreads();
    if (threadIdx.x < 128) {
        float a = sh[0][threadIdx.x] + sh[1][threadIdx.x] + sh[2][threadIdx.x] + sh[3][threadIdx.x];
        partials[blockIdx.x * 128 + threadIdx.x] = a;
    }
}

// parallel finalize: 1024 threads, 8 slices per channel, LDS tree
__global__ __launch_bounds__(1024) void bn_finalize(const float* __restrict__ partials, int nblk,
                            const float* __restrict__ gamma, const float* __restrict__ beta,
                            float* __restrict__ scsh, int n) {
    __shared__ float red[8][128];
    __shared__ float tot[128];
    int t = threadIdx.x;
    int ch = t & 127, sl = t >> 7;
    float a = 0.f;
#pragma unroll 8
    for (int b = sl; b < nblk; b += 8) a += partials[b * 128 + ch];
    red[sl][ch] = a;
    __syncthreads();
    if (t < 128) {
        float s = 0.f;
#pragma unroll
        for (int i = 0; i < 8; ++i) s += red[i][t];
        tot[t] = s;
    }
    __syncthreads();
    if (t < 64) {
        float mean = tot[t] / (float)n;
        float var = tot[64 + t] / (float)n - mean * mean;
        float sc = rsqrtf(var + 1e-5f) * gamma[t];
        scsh[t] = sc;
        scsh[64 + t] = beta[t] - mean * sc;
    }
}

// ---------- tiled bn+relu+GEMM: h(bf16) = relu(y*sc+sh) @ W ----------
// 256 threads, 128-node tile, 4x8 outputs per lane. kc loop NOT unrolled
// (R7: full unroll -> live-range explosion -> spills).
struct alignas(16) us8 { unsigned short v[8]; };
__global__ __launch_bounds__(256, 2) void bn_relu_gemm(const float* __restrict__ y,
                             const float* __restrict__ scsh, const float* __restrict__ W,
                             unsigned short* __restrict__ hb, int n) {
    __shared__ float4 yt4[128 * 16];
    __shared__ float4 wt4[64 * 16];
    float* wt = (float*)wt4;
    const int t = threadIdx.x;          // 256 threads
    const int base = blockIdx.x * 128;

    // stage W^T: read W[k][c0..c0+3] coalesced, scatter-transpose into wt[c][k]
    const float4* W4 = (const float4*)W;
#pragma unroll
    for (int i = 0; i < 4; ++i) {
        int g = t + 256 * i;
        int k = g >> 4;                 // W row = input channel
        int c0 = (g & 15) << 2;         // output-channel group
        float4 wv = W4[g];
        float wvf[4] = {wv.x, wv.y, wv.z, wv.w};
#pragma unroll
        for (int j = 0; j < 4; ++j) {
            int c = c0 + j;
            wt[c * 64 + (((k >> 2) ^ ((c >> 2) & 15)) << 2) + (k & 3)] = wvf[j];
        }
    }
    // stage yt = relu(y*sc+sh) (128x64 = 2048 float4)
    const float4* y4 = (const float4*)y;
#pragma unroll
    for (int i = 0; i < 8; ++i) {
        int g = t + 256 * i;
        int r = g >> 4, kc = g & 15;
        int row = base + r;
        float4 v = make_float4(0.f, 0.f, 0.f, 0.f);
        if (row < n) v = y4[(size_t)row * 16 + kc];
        int c0 = kc << 2;
        v.x = fmaxf(v.x * scsh[c0 + 0] + scsh[64 + c0 + 0], 0.f);
        v.y = fmaxf(v.y * scsh[c0 + 1] + scsh[64 + c0 + 1], 0.f);
        v.z = fmaxf(v.z * scsh[c0 + 2] + scsh[64 + c0 + 2], 0.f);
        v.w = fmaxf(v.w * scsh[c0 + 3] + scsh[64 + c0 + 3], 0.f);
        yt4[r * 16 + (kc ^ ((r >> 2) & 15))] = v;
    }
    __syncthreads();

    const int w = t >> 6;              // wave 0..3 -> nodes [w*32, w*32+32)
    const int lane = t & 63;
    const int ng = lane >> 3;          // 0..7
    const int cg = lane & 7;           // 0..7
    const int rl = w * 32 + ng * 4;    // local rows rl..rl+3
    const int c0 = cg * 8;             // channels c0..c0+7
    const int sa = (rl >> 2) & 15;     // same for all 4 rows
    float acc[4][8];
#pragma unroll
    for (int m = 0; m < 4; ++m)
#pragma unroll
        for (int j = 0; j < 8; ++j) acc[m][j] = 0.f;

#pragma unroll 1
    for (int kc = 0; kc < 16; ++kc) {
        float4 a[4];
#pragma unroll
        for (int m = 0; m < 4; ++m) a[m] = yt4[(rl + m) * 16 + (kc ^ sa)];
#pragma unroll
        for (int j = 0; j < 8; ++j) {
            int c = c0 + j;
            float4 b = wt4[c * 16 + (kc ^ ((c >> 2) & 15))];
#pragma unroll
            for (int m = 0; m < 4; ++m)
                acc[m][j] += a[m].x * b.x + a[m].y * b.y +
                             a[m].z * b.z + a[m].w * b.w;
        }
    }

#pragma unroll
    for (int m = 0; m < 4; ++m) {
        int row = base + rl + m;
        if (row < n) {
            us8 p;
#pragma unroll
            for (int j = 0; j < 8; ++j) p.v[j] = f2bf(acc[m][j]);
            *(us8*)&hb[((size_t)row << 6) | c0] = p;
        }
    }
}

// ---------- final: out[g] = (pooled[g]/cnt) @ Wout + bout ----------
__global__ void final_out(const float* __restrict__ pooled, const int* __restrict__ cnt,
                          const float* __restrict__ Wout, const float* __restrict__ bout,
                          float* __restrict__ out, int G) {
    int idx = blockIdx.x * blockDim.x + threadIdx.x;
    if (idx >= G * 4) return;
    int g = idx >> 2, o = idx & 3;
    float inv = 1.f / fmaxf((float)cnt[g], 1.f);
    float a = 0.f;
    for (int k = 0; k < 64; ++k) a += pooled[g * 64 + k] * Wout[k * 4 + o];
    out[idx] = a * inv + bout[o];
}

extern "C" void kernel_launch(void* const* d_in, const int* in_sizes, int n_in,
                              void* d_out, int out_size, void* d_ws, size_t ws_size,
                              hipStream_t stream) {
    const int N = in_sizes[0];
    const int E = in_sizes[6] / 2;
    const int T = in_sizes[8] / 64;
    const int G = out_size / 4;

    const int*   type_ids = (const int*)d_in[0];
    const float* fc   = (const float*)d_in[1];
    const float* fgm  = (const float*)d_in[2];
    const float* fpos = (const float*)d_in[3];
    const float* fr   = (const float*)d_in[4];
    const float* fvid = (const float*)d_in[5];
    const int*   ei   = (const int*)d_in[6];
    const int*   batch = (const int*)d_in[7];
    const float* W1 = (const float*)d_in[8];
    const float* b1 = (const float*)d_in[9];
    const float* W2 = (const float*)d_in[10];
    const float* b2 = (const float*)d_in[11];
    const float* Wg0 = (const float*)d_in[12];
    const float* bg0 = (const float*)d_in[13];
    const float* Wg1 = (const float*)d_in[14];
    const float* bg1 = (const float*)d_in[15];
    const float* Wg2 = (const float*)d_in[16];
    const float* bg2 = (const float*)d_in[17];
    const float* gam0 = (const float*)d_in[18];
    const float* bet0 = (const float*)d_in[19];
    const float* gam1 = (const float*)d_in[20];
    const float* bet1 = (const float*)d_in[21];
    const float* Wout = (const float*)d_in[22];
    const float* bout = (const float*)d_in[23];

    const int* e_src = ei;
    const int* e_dst = ei + E;

    // ---- workspace layout ----
    char* ws = (char*)d_ws;
    size_t o = 0;
    auto alloc = [&](size_t bytes) -> char* {
        char* p = ws + o;
        o += (bytes + 255) & ~(size_t)255;
        return p;
    };
    const int NBLK_BN = 256;
    const int NTILES = (N + SCAN_TILE - 1) / SCAN_TILE;
    unsigned short* hb = (unsigned short*)alloc((size_t)N * 64 * 2);
    float* y        = (float*)alloc((size_t)N * 64 * 4);
    int*   deg      = (int*)alloc((size_t)N * 4);
    float* dinv     = (float*)alloc((size_t)N * 4);
    int*   off      = (int*)alloc((size_t)(N + 1) * 4);
    int*   cursor   = (int*)alloc((size_t)N * 4);
    int*   loc      = (int*)alloc((size_t)N * 4);
    int*   tilesum  = (int*)alloc((size_t)NTILES * 4);
    int*   tileoff  = (int*)alloc((size_t)NTILES * 4);
    int2*  csrBuf   = (int2*)alloc(((size_t)E + 24) * 8);
    int2*  csr      = csrBuf + 1;      // front pad: csr[-1] valid
    float* part0    = (float*)alloc((size_t)NBLK_BN * 128 * 4);
    float* part1    = (float*)alloc((size_t)NBLK_BN * 128 * 4);
    float* scsh0    = (float*)alloc(128 * 4);
    float* scsh1    = (float*)alloc(128 * 4);
    float* pooled   = (float*)alloc((size_t)G * 64 * 4);
    int*   cnt      = (int*)alloc((size_t)G * 4);
    float* M1       = (float*)alloc((size_t)T * 64 * 4);
    float* M2       = (float*)alloc(5 * 64 * 4);
    float* cvec     = (float*)alloc(64 * 4);
    (void)ws_size;

    hipMemsetAsync(deg, 0, (size_t)N * 4, stream);
    hipMemsetAsync(csrBuf, 0, 8, stream);              // front pad entry
    hipMemsetAsync(csr + E, 0, 16 * 8, stream);        // tail pad (16 entries)
    hipMemsetAsync(pooled, 0, (size_t)G * 64 * 4, stream);
    hipMemsetAsync(cnt, 0, (size_t)G * 4, stream);

    const int waves_per_blk = 4;                   // 256 threads
    const int nblk_nodes = (N + waves_per_blk - 1) / waves_per_blk;
    const int nblk_gemm = (N + 127) / 128;

    precompute_mats<<<1, 256, 0, stream>>>(W1, b1, W2, b2, Wg0, M1, M2, cvec, T);
    node_embed<<<nblk_nodes, 256, 0, stream>>>(type_ids, fc, fgm, fpos, fr, fvid, M1, M2, cvec, hb, N);

    count_deg<<<(E + 255) / 256, 256, 0, stream>>>(e_dst, deg, E);
    scan_local<<<NTILES, SCAN_TILE, 0, stream>>>(deg, loc, tilesum, dinv, N);
    scan_tiles<<<1, 64, 0, stream>>>(tilesum, tileoff, NTILES);
    scan_add<<<(N + 255) / 256, 256, 0, stream>>>(loc, tileoff, off, cursor, N);
    fill_csr<<<(E + 255) / 256, 256, 0, stream>>>(e_src, e_dst, dinv, cursor, csr, E);

    // layer 0
    conv_gather<<<nblk_nodes, 256, 0, stream>>>(hb, off, csr, dinv, bg0, y, N);
    bn_stats<<<NBLK_BN, 256, 0, stream>>>(y, part0, N);
    bn_finalize<<<1, 1024, 0, stream>>>(part0, NBLK_BN, gam0, bet0, scsh0, N);
    bn_relu_gemm<<<nblk_gemm, 256, 0, stream>>>(y, scsh0, Wg1, hb, N);

    // layer 1
    conv_gather<<<nblk_nodes, 256, 0, stream>>>(hb, off, csr, dinv, bg1, y, N);
    bn_stats<<<NBLK_BN, 256, 0, stream>>>(y, part1, N);
    bn_finalize<<<1, 1024, 0, stream>>>(part1, NBLK_BN, gam1, bet1, scsh1, N);
    bn_relu_gemm<<<nblk_gemm, 256, 0, stream>>>(y, scsh1, Wg2, hb, N);

    // layer 2: conv + relu + segmented mean-pool fused
    {
        int waves = (N + POOL_CHUNK - 1) / POOL_CHUNK;
        int blocks = (waves + waves_per_blk - 1) / waves_per_blk;
        conv_relu_pool<<<blocks, 256, 0, stream>>>(hb, off, csr, dinv, bg2, batch,
                                                   pooled, cnt, N);
    }

    final_out<<<(G * 4 + 255) / 256, 256, 0, stream>>>(pooled, cnt, Wout, bout, (float*)d_out, G);
}

// Round 13
// 288.865 us; speedup vs baseline: 1.2507x; 1.0603x over previous
//
#include <hip/hip_runtime.h>
#include <hip/hip_bf16.h>

// GCN: embed -> (conv -> bn -> relu) x2 -> conv(+relu+pool fused) -> linear
// H = 64.
// R12: (a) gather table stores h*dinv (bf16) -> CSR is src-index ONLY (4B):
//      fill_csr writeback halves, conv weight math disappears (edge weight
//      == dinv[dst], hoisted). (b) pool via graph_off slices: one atomic per
//      lane per slice (262K vs 800K atomic-ops). (R7/R8/R11 lessons kept.)

// bf16 helpers
__device__ __forceinline__ unsigned short f2bf(float f) {
    unsigned int x = (unsigned int)__float_as_int(f);
    x += 0x7fffu + ((x >> 16) & 1u);
    return (unsigned short)(x >> 16);
}

// ---------- tiny precompute: fold one-hot/numeric linears through Wg0 ----------
__global__ void precompute_mats(const float* __restrict__ W1, const float* __restrict__ b1,
                                const float* __restrict__ W2, const float* __restrict__ b2,
                                const float* __restrict__ Wg0,
                                float* __restrict__ M1, float* __restrict__ M2,
                                float* __restrict__ cvec, int T) {
    int tid = threadIdx.x;
    for (int idx = tid; idx < T * 64; idx += blockDim.x) {
        int t = idx >> 6, c = idx & 63;
        float a = 0.f;
        for (int k = 0; k < 64; ++k) a += W1[t * 64 + k] * Wg0[k * 64 + c];
        M1[idx] = a;
    }
    for (int idx = tid; idx < 5 * 64; idx += blockDim.x) {
        int j = idx >> 6, c = idx & 63;
        float a = 0.f;
        for (int k = 0; k < 64; ++k) a += W2[j * 64 + k] * Wg0[(64 + k) * 64 + c];
        M2[idx] = a;
    }
    for (int c = tid; c < 64; c += blockDim.x) {
        float a = 0.f;
        for (int k = 0; k < 64; ++k)
            a += b1[k] * Wg0[k * 64 + c] + b2[k] * Wg0[(64 + k) * 64 + c];
        cvec[c] = a;
    }
}

// ---------- node features -> hb[i] = h0[i] * dinv[i] (bf16) ----------
__global__ void node_embed(const int* __restrict__ type_ids,
                           const float* __restrict__ f0, const float* __restrict__ f1,
                           const float* __restrict__ f2, const float* __restrict__ f3,
                           const float* __restrict__ f4,
                           const float* __restrict__ M1, const float* __restrict__ M2,
                           const float* __restrict__ cvec, const float* __restrict__ dinv,
                           unsigned short* __restrict__ hb, int n) {
    int i = blockIdx.x * (blockDim.x >> 6) + (threadIdx.x >> 6);
    int lane = threadIdx.x & 63;
    if (i >= n) return;
    int t = type_ids[i];
    float a = M1[t * 64 + lane] + cvec[lane];
    a += f0[i] * M2[0 * 64 + lane];
    a += f1[i] * M2[1 * 64 + lane];
    a += f2[i] * M2[2 * 64 + lane];
    a += f3[i] * M2[3 * 64 + lane];
    a += f4[i] * M2[4 * 64 + lane];
    hb[((unsigned)i << 6) | lane] = f2bf(a * dinv[i]);
}

// ---------- degree / CSR build ----------
__global__ void count_deg(const int* __restrict__ dst, int* __restrict__ deg, int e) {
    int i = blockIdx.x * blockDim.x + threadIdx.x;
    if (i < e) atomicAdd(&deg[dst[i]], 1);
}

// ---------- 3-phase scan (also emits dinv) ----------
#define SCAN_TILE 1024
__global__ void scan_local(const int* __restrict__ deg, int* __restrict__ loc,
                           int* __restrict__ tilesum, float* __restrict__ dinv, int n) {
    __shared__ int wsum[16];
    __shared__ int wexcl[16];
    const int tid = threadIdx.x;
    const int lane = tid & 63, w = tid >> 6;
    int i = blockIdx.x * SCAN_TILE + tid;
    int v = (i < n) ? deg[i] : 0;
    if (i < n) dinv[i] = rsqrtf((float)(v + 1));  // +1 self loop
    int incl = v;
#pragma unroll
    for (int ofs = 1; ofs < 64; ofs <<= 1) {
        int t = __shfl_up(incl, (unsigned)ofs, 64);
        if (lane >= ofs) incl += t;
    }
    if (lane == 63) wsum[w] = incl;
    __syncthreads();
    if (w == 0 && lane < 16) {
        int s = wsum[lane];
        int sc = s;
#pragma unroll
        for (int ofs = 1; ofs < 16; ofs <<= 1) {
            int t = __shfl_up(sc, (unsigned)ofs, 64);
            if (lane >= ofs) sc += t;
        }
        wexcl[lane] = sc - s;
        if (lane == 15) wsum[15] = sc;
    }
    __syncthreads();
    if (i < n) loc[i] = wexcl[w] + incl;
    if (tid == 0) tilesum[blockIdx.x] = wsum[15];
}

__global__ void scan_tiles(int* __restrict__ tilesum, int* __restrict__ tileoff, int nt) {
    int lane = threadIdx.x;
    int v = (lane < nt) ? tilesum[lane] : 0;
    int incl = v;
#pragma unroll
    for (int ofs = 1; ofs < 64; ofs <<= 1) {
        int t = __shfl_up(incl, (unsigned)ofs, 64);
        if (lane >= ofs) incl += t;
    }
    if (lane < nt) tileoff[lane] = incl - v;
}

__global__ void scan_add(const int* __restrict__ loc, const int* __restrict__ tileoff,
                         int* __restrict__ off, int* __restrict__ cursor, int n) {
    int i = blockIdx.x * blockDim.x + threadIdx.x;
    if (i >= n) return;
    int val = tileoff[i / SCAN_TILE] + loc[i];
    off[i + 1] = val;
    if (i + 1 < n) cursor[i + 1] = val;
    if (i == 0) { off[0] = 0; cursor[0] = 0; }
}

// ---------- fill CSR: ONE 4B store per edge (src only) ----------
__global__ void fill_csr(const int* __restrict__ src, const int* __restrict__ dst,
                         int* __restrict__ cursor, int* __restrict__ csr_i, int e) {
    int i = blockIdx.x * blockDim.x + threadIdx.x;
    if (i >= e) return;
    int s = src[i], d = dst[i];
    int pos = atomicAdd(&cursor[d], 1);
    csr_i[pos] = s;
}

// ---------- graph offsets from sorted batch ----------
__global__ void build_graph_off(const int* __restrict__ batch, int* __restrict__ go,
                                int n, int G) {
    int i = blockIdx.x * blockDim.x + threadIdx.x;
    if (i >= n) return;
    int b = batch[i];
    if (i == 0) {
        for (int g = 0; g <= b; ++g) go[g] = 0;
    } else {
        int p = batch[i - 1];
        if (p != b) for (int g = p + 1; g <= b; ++g) go[g] = i;
    }
    if (i == n - 1) {
        for (int g = b + 1; g <= G; ++g) go[g] = n;
    }
}

// ---------- conv gather core: 8 lanes/edge, uint4 rows, shfl-tree reduce ----------
// hb holds h*dinv(src) in bf16; edge contribution needs only *dinv[dst] which
// is applied once after reduction. Row N of hb is zeros (mask target).
__device__ __forceinline__ void gather_add(float acc[8], uint4 v) {
    acc[0] += __uint_as_float(v.x << 16);
    acc[1] += __uint_as_float(v.x & 0xffff0000u);
    acc[2] += __uint_as_float(v.y << 16);
    acc[3] += __uint_as_float(v.y & 0xffff0000u);
    acc[4] += __uint_as_float(v.z << 16);
    acc[5] += __uint_as_float(v.z & 0xffff0000u);
    acc[6] += __uint_as_float(v.w << 16);
    acc[7] += __uint_as_float(v.w & 0xffff0000u);
}

__device__ __forceinline__ void node_aggregate(float acc[8],
                                               const unsigned short* __restrict__ hb,
                                               const int* __restrict__ csr_i,
                                               int i, int b, int deg, int N,
                                               int eg, int cc) {
#pragma unroll
    for (int q = 0; q < 8; ++q) acc[q] = 0.f;
    int nb = (deg + 8) >> 3;  // ceil((deg+1)/8)
#pragma unroll 1
    for (int t = 0; t < nb; t += 2) {
        int j = (t << 3) + eg;
        int j2 = j + 8;
        int eA = csr_i[b + j - 1];   // unpredicated; front/tail padded
        int eB = csr_i[b + j2 - 1];
        int sA = (j == 0) ? i : ((j <= deg) ? eA : N);
        int sB = (j2 <= deg) ? eB : N;
        uint4 vA = *(const uint4*)&hb[((unsigned)sA << 6) + (cc << 3)];
        uint4 vB = *(const uint4*)&hb[((unsigned)sB << 6) + (cc << 3)];
        gather_add(acc, vA);
        gather_add(acc, vB);
    }
#pragma unroll
    for (int q = 0; q < 8; ++q) {
        acc[q] += __shfl_xor(acc[q], 8, 64);
        acc[q] += __shfl_xor(acc[q], 16, 64);
        acc[q] += __shfl_xor(acc[q], 32, 64);
    }
}

__global__ void conv_gather(const unsigned short* __restrict__ hb,
                            const int* __restrict__ off, const int* __restrict__ csr_i,
                            const float* __restrict__ dinv,
                            const float* __restrict__ bias, float* __restrict__ out,
                            int n) {
    int i = blockIdx.x * (blockDim.x >> 6) + (threadIdx.x >> 6);
    if (i >= n) return;
    const int lane = threadIdx.x & 63;
    const int eg = lane >> 3, cc = lane & 7;
    int b = off[i], e = off[i + 1];
    float di = dinv[i];
    float acc[8];
    node_aggregate(acc, hb, csr_i, i, b, e - b, n, eg, cc);
    if (eg == 0) {
        const float4* b4 = (const float4*)bias;
        float4 bb0 = b4[cc * 2], bb1 = b4[cc * 2 + 1];
        float4 o0 = make_float4(acc[0] * di + bb0.x, acc[1] * di + bb0.y,
                                acc[2] * di + bb0.z, acc[3] * di + bb0.w);
        float4 o1 = make_float4(acc[4] * di + bb1.x, acc[5] * di + bb1.y,
                                acc[6] * di + bb1.z, acc[7] * di + bb1.w);
        float4* o = (float4*)&out[((size_t)i << 6) + (cc << 3)];
        o[0] = o0;
        o[1] = o1;
    }
}

// ---------- conv + relu + mean-pool (layer 2): one wave per (graph, slice) ----------
#define POOL_SLICES 16
__global__ void conv_relu_pool(const unsigned short* __restrict__ hb,
                               const int* __restrict__ off, const int* __restrict__ csr_i,
                               const float* __restrict__ dinv,
                               const float* __restrict__ bias, const int* __restrict__ go,
                               float* __restrict__ pooled, int* __restrict__ cnt,
                               int n, int G) {
    int wave = blockIdx.x * (blockDim.x >> 6) + (threadIdx.x >> 6);
    int g = wave >> 4, k = wave & (POOL_SLICES - 1);
    if (g >= G) return;
    const int lane = threadIdx.x & 63;
    const int eg = lane >> 3, cc = lane & 7;
    int gs = go[g], ge = go[g + 1];
    int cntg = ge - gs;
    if (k == 0 && lane == 0) cnt[g] = cntg;   // plain store, deterministic
    if (cntg == 0) return;
    int per = (cntg + POOL_SLICES - 1) >> 4;
    int s0 = gs + k * per;
    int s1 = min(ge, s0 + per);
    if (s0 >= s1) return;
    const float4* b4 = (const float4*)bias;
    float4 bb0 = b4[cc * 2], bb1 = b4[cc * 2 + 1];
    float bl[8] = {bb0.x, bb0.y, bb0.z, bb0.w, bb1.x, bb1.y, bb1.z, bb1.w};
    float accp[8];
#pragma unroll
    for (int q = 0; q < 8; ++q) accp[q] = 0.f;
    for (int i = s0; i < s1; ++i) {
        int b = off[i], e = off[i + 1];
        float di = dinv[i];
        float acc[8];
        node_aggregate(acc, hb, csr_i, i, b, e - b, n, eg, cc);
#pragma unroll
        for (int q = 0; q < 8; ++q) accp[q] += fmaxf(acc[q] * di + bl[q], 0.f);
    }
    // all lanes hold the full slice sum for their cc; lane (eg,cc) flushes
    // channel cc*8+eg -> exactly one atomic per lane.
    atomicAdd(&pooled[g * 64 + (cc << 3) + eg], accp[eg]);
}

// ---------- batchnorm stats: per-block partials ----------
__global__ void bn_stats(const float* __restrict__ y, float* __restrict__ partials, int n) {
    __shared__ float sh[4][128];
    int lane = threadIdx.x & 63;
    int w = threadIdx.x >> 6;
    int waves_per_blk = blockDim.x >> 6;
    float s = 0.f, ss = 0.f;
    for (int i = blockIdx.x * waves_per_blk + w; i < n; i += gridDim.x * waves_per_blk) {
        float v = y[((size_t)i << 6) | lane];
        s += v;
        ss += v * v;
    }
    sh[w][lane] = s;
    sh[w][64 + lane] = ss;
    __syncthreads();
    if (threadIdx.x < 128) {
        float a = sh[0][threadIdx.x] + sh[1][threadIdx.x] + sh[2][threadIdx.x] + sh[3][threadIdx.x];
        partials[blockIdx.x * 128 + threadIdx.x] = a;
    }
}

// parallel finalize: 1024 threads, 8 slices per channel, LDS tree
__global__ __launch_bounds__(1024) void bn_finalize(const float* __restrict__ partials, int nblk,
                            const float* __restrict__ gamma, const float* __restrict__ beta,
                            float* __restrict__ scsh, int n) {
    __shared__ float red[8][128];
    __shared__ float tot[128];
    int t = threadIdx.x;
    int ch = t & 127, sl = t >> 7;
    float a = 0.f;
#pragma unroll 8
    for (int b = sl; b < nblk; b += 8) a += partials[b * 128 + ch];
    red[sl][ch] = a;
    __syncthreads();
    if (t < 128) {
        float s = 0.f;
#pragma unroll
        for (int i = 0; i < 8; ++i) s += red[i][t];
        tot[t] = s;
    }
    __syncthreads();
    if (t < 64) {
        float mean = tot[t] / (float)n;
        float var = tot[64 + t] / (float)n - mean * mean;
        float sc = rsqrtf(var + 1e-5f) * gamma[t];
        scsh[t] = sc;
        scsh[64 + t] = beta[t] - mean * sc;
    }
}

// ---------- tiled bn+relu+GEMM: hb = (relu(y*sc+sh) @ W) * dinv[row], bf16 ----------
// 256 threads, 128-node tile, 4x8 outputs per lane. kc loop NOT unrolled
// (R7: full unroll -> live-range explosion -> spills).
struct alignas(16) us8 { unsigned short v[8]; };
__global__ __launch_bounds__(256, 2) void bn_relu_gemm(const float* __restrict__ y,
                             const float* __restrict__ scsh, const float* __restrict__ W,
                             const float* __restrict__ dinv,
                             unsigned short* __restrict__ hb, int n) {
    __shared__ float4 yt4[128 * 16];
    __shared__ float4 wt4[64 * 16];
    float* wt = (float*)wt4;
    const int t = threadIdx.x;          // 256 threads
    const int base = blockIdx.x * 128;

    // stage W^T: read W[k][c0..c0+3] coalesced, scatter-transpose into wt[c][k]
    const float4* W4 = (const float4*)W;
#pragma unroll
    for (int i = 0; i < 4; ++i) {
        int g = t + 256 * i;
        int k = g >> 4;                 // W row = input channel
        int c0 = (g & 15) << 2;         // output-channel group
        float4 wv = W4[g];
        float wvf[4] = {wv.x, wv.y, wv.z, wv.w};
#pragma unroll
        for (int j = 0; j < 4; ++j) {
            int c = c0 + j;
            wt[c * 64 + (((k >> 2) ^ ((c >> 2) & 15)) << 2) + (k & 3)] = wvf[j];
        }
    }
    // stage yt = relu(y*sc+sh) (128x64 = 2048 float4)
    const float4* y4 = (const float4*)y;
#pragma unroll
    for (int i = 0; i < 8; ++i) {
        int g = t + 256 * i;
        int r = g >> 4, kc = g & 15;
        int row = base + r;
        float4 v = make_float4(0.f, 0.f, 0.f, 0.f);
        if (row < n) v = y4[(size_t)row * 16 + kc];
        int c0 = kc << 2;
        v.x = fmaxf(v.x * scsh[c0 + 0] + scsh[64 + c0 + 0], 0.f);
        v.y = fmaxf(v.y * scsh[c0 + 1] + scsh[64 + c0 + 1], 0.f);
        v.z = fmaxf(v.z * scsh[c0 + 2] + scsh[64 + c0 + 2], 0.f);
        v.w = fmaxf(v.w * scsh[c0 + 3] + scsh[64 + c0 + 3], 0.f);
        yt4[r * 16 + (kc ^ ((r >> 2) & 15))] = v;
    }
    __syncthreads();

    const int w = t >> 6;              // wave 0..3 -> nodes [w*32, w*32+32)
    const int lane = t & 63;
    const int ng = lane >> 3;          // 0..7
    const int cg = lane & 7;           // 0..7
    const int rl = w * 32 + ng * 4;    // local rows rl..rl+3
    const int c0 = cg * 8;             // channels c0..c0+7
    const int sa = (rl >> 2) & 15;     // same for all 4 rows
    float acc[4][8];
#pragma unroll
    for (int m = 0; m < 4; ++m)
#pragma unroll
        for (int j = 0; j < 8; ++j) acc[m][j] = 0.f;

#pragma unroll 1
    for (int kc = 0; kc < 16; ++kc) {
        float4 a[4];
#pragma unroll
        for (int m = 0; m < 4; ++m) a[m] = yt4[(rl + m) * 16 + (kc ^ sa)];
#pragma unroll
        for (int j = 0; j < 8; ++j) {
            int c = c0 + j;
            float4 b = wt4[c * 16 + (kc ^ ((c >> 2) & 15))];
#pragma unroll
            for (int m = 0; m < 4; ++m)
                acc[m][j] += a[m].x * b.x + a[m].y * b.y +
                             a[m].z * b.z + a[m].w * b.w;
        }
    }

#pragma unroll
    for (int m = 0; m < 4; ++m) {
        int row = base + rl + m;
        if (row < n) {
            float dv = dinv[row];
            us8 p;
#pragma unroll
            for (int j = 0; j < 8; ++j) p.v[j] = f2bf(acc[m][j] * dv);
            *(us8*)&hb[((size_t)row << 6) | c0] = p;
        }
    }
}

// ---------- final: out[g] = (pooled[g]/cnt) @ Wout + bout ----------
__global__ void final_out(const float* __restrict__ pooled, const int* __restrict__ cnt,
                          const float* __restrict__ Wout, const float* __restrict__ bout,
                          float* __restrict__ out, int G) {
    int idx = blockIdx.x * blockDim.x + threadIdx.x;
    if (idx >= G * 4) return;
    int g = idx >> 2, o = idx & 3;
    float inv = 1.f / fmaxf((float)cnt[g], 1.f);
    float a = 0.f;
    for (int k = 0; k < 64; ++k) a += pooled[g * 64 + k] * Wout[k * 4 + o];
    out[idx] = a * inv + bout[o];
}

extern "C" void kernel_launch(void* const* d_in, const int* in_sizes, int n_in,
                              void* d_out, int out_size, void* d_ws, size_t ws_size,
                              hipStream_t stream) {
    const int N = in_sizes[0];
    const int E = in_sizes[6] / 2;
    const int T = in_sizes[8] / 64;
    const int G = out_size / 4;

    const int*   type_ids = (const int*)d_in[0];
    const float* fc   = (const float*)d_in[1];
    const float* fgm  = (const float*)d_in[2];
    const float* fpos = (const float*)d_in[3];
    const float* fr   = (const float*)d_in[4];
    const float* fvid = (const float*)d_in[5];
    const int*   ei   = (const int*)d_in[6];
    const int*   batch = (const int*)d_in[7];
    const float* W1 = (const float*)d_in[8];
    const float* b1 = (const float*)d_in[9];
    const float* W2 = (const float*)d_in[10];
    const float* b2 = (const float*)d_in[11];
    const float* Wg0 = (const float*)d_in[12];
    const float* bg0 = (const float*)d_in[13];
    const float* Wg1 = (const float*)d_in[14];
    const float* bg1 = (const float*)d_in[15];
    const float* Wg2 = (const float*)d_in[16];
    const float* bg2 = (const float*)d_in[17];
    const float* gam0 = (const float*)d_in[18];
    const float* bet0 = (const float*)d_in[19];
    const float* gam1 = (const float*)d_in[20];
    const float* bet1 = (const float*)d_in[21];
    const float* Wout = (const float*)d_in[22];
    const float* bout = (const float*)d_in[23];

    const int* e_src = ei;
    const int* e_dst = ei + E;

    // ---- workspace layout ----
    char* ws = (char*)d_ws;
    size_t o = 0;
    auto alloc = [&](size_t bytes) -> char* {
        char* p = ws + o;
        o += (bytes + 255) & ~(size_t)255;
        return p;
    };
    const int NBLK_BN = 256;
    const int NTILES = (N + SCAN_TILE - 1) / SCAN_TILE;
    unsigned short* hb = (unsigned short*)alloc((size_t)(N + 1) * 64 * 2); // +1 zero row
    float* y        = (float*)alloc((size_t)N * 64 * 4);
    int*   deg      = (int*)alloc((size_t)N * 4);
    float* dinv     = (float*)alloc((size_t)N * 4);
    int*   off      = (int*)alloc((size_t)(N + 1) * 4);
    int*   cursor   = (int*)alloc((size_t)N * 4);
    int*   loc      = (int*)alloc((size_t)N * 4);
    int*   tilesum  = (int*)alloc((size_t)NTILES * 4);
    int*   tileoff  = (int*)alloc((size_t)NTILES * 4);
    int*   csrBuf   = (int*)alloc(((size_t)E + 24) * 4);
    int*   csr_i    = csrBuf + 1;      // front pad: csr_i[-1] valid
    int*   go       = (int*)alloc((size_t)(G + 1) * 4);
    float* part0    = (float*)alloc((size_t)NBLK_BN * 128 * 4);
    float* part1    = (float*)alloc((size_t)NBLK_BN * 128 * 4);
    float* scsh0    = (float*)alloc(128 * 4);
    float* scsh1    = (float*)alloc(128 * 4);
    float* pooled   = (float*)alloc((size_t)G * 64 * 4);
    int*   cnt      = (int*)alloc((size_t)G * 4);
    float* M1       = (float*)alloc((size_t)T * 64 * 4);
    float* M2       = (float*)alloc(5 * 64 * 4);
    float* cvec     = (float*)alloc(64 * 4);
    (void)ws_size;

    hipMemsetAsync(deg, 0, (size_t)N * 4, stream);
    hipMemsetAsync(csrBuf, 0, 4, stream);             // front pad entry
    hipMemsetAsync(csr_i + E, 0, 16 * 4, stream);     // tail pad (16 entries)
    hipMemsetAsync(hb + (size_t)N * 64, 0, 128, stream);  // zero row N (mask target)
    hipMemsetAsync(pooled, 0, (size_t)G * 64 * 4, stream);

    const int waves_per_blk = 4;                   // 256 threads
    const int nblk_nodes = (N + waves_per_blk - 1) / waves_per_blk;
    const int nblk_gemm = (N + 127) / 128;

    // graph structure (dinv needed by node_embed)
    count_deg<<<(E + 255) / 256, 256, 0, stream>>>(e_dst, deg, E);
    scan_local<<<NTILES, SCAN_TILE, 0, stream>>>(deg, loc, tilesum, dinv, N);
    scan_tiles<<<1, 64, 0, stream>>>(tilesum, tileoff, NTILES);
    scan_add<<<(N + 255) / 256, 256, 0, stream>>>(loc, tileoff, off, cursor, N);
    fill_csr<<<(E + 255) / 256, 256, 0, stream>>>(e_src, e_dst, cursor, csr_i, E);
    build_graph_off<<<(N + 255) / 256, 256, 0, stream>>>(batch, go, N, G);

    precompute_mats<<<1, 256, 0, stream>>>(W1, b1, W2, b2, Wg0, M1, M2, cvec, T);
    node_embed<<<nblk_nodes, 256, 0, stream>>>(type_ids, fc, fgm, fpos, fr, fvid,
                                               M1, M2, cvec, dinv, hb, N);

    // layer 0
    conv_gather<<<nblk_nodes, 256, 0, stream>>>(hb, off, csr_i, dinv, bg0, y, N);
    bn_stats<<<NBLK_BN, 256, 0, stream>>>(y, part0, N);
    bn_finalize<<<1, 1024, 0, stream>>>(part0, NBLK_BN, gam0, bet0, scsh0, N);
    bn_relu_gemm<<<nblk_gemm, 256, 0, stream>>>(y, scsh0, Wg1, dinv, hb, N);

    // layer 1
    conv_gather<<<nblk_nodes, 256, 0, stream>>>(hb, off, csr_i, dinv, bg1, y, N);
    bn_stats<<<NBLK_BN, 256, 0, stream>>>(y, part1, N);
    bn_finalize<<<1, 1024, 0, stream>>>(part1, NBLK_BN, gam1, bet1, scsh1, N);
    bn_relu_gemm<<<nblk_gemm, 256, 0, stream>>>(y, scsh1, Wg2, dinv, hb, N);

    // layer 2: conv + relu + graph-sliced mean-pool
    {
        int waves = G * POOL_SLICES;
        int blocks = (waves + waves_per_blk - 1) / waves_per_blk;
        conv_relu_pool<<<blocks, 256, 0, stream>>>(hb, off, csr_i, dinv, bg2, go,
                                                   pooled, cnt, N, G);
    }

    final_out<<<(G * 4 + 255) / 256, 256, 0, stream>>>(pooled, cnt, Wout, bout, (float*)d_out, G);
}